// Round 19
// baseline (153.902 us; speedup 1.0000x reference)
//
#include <hip/hip_runtime.h>

#define HH 64
#define WW 64
#define TT 16
#define NPIX (HH * WW * TT)   // 65536
#define HALO 10               // 4 + 2*3
#define HWH  (HALO * HALO)    // 100 halo (h,w) positions
#define CH_SZ (HWH * TT)      // 1600 floats per channel
#define NCH 15                // gui(9, prescaled) + est(3) + var(3, x gamma^2)

// lane i <- lane i-1 within 16-lane DPP rows (row_shr:1), 0-fill at row start.
__device__ __forceinline__ float dpp_up1(float x) {
    return __int_as_float(__builtin_amdgcn_update_dpp(
        0, __float_as_int(x), 0x111, 0xF, 0xF, true));
}
// lane i <- lane i+1 within 16-lane DPP rows (row_shl:1), 0-fill at row end.
__device__ __forceinline__ float dpp_dn1(float x) {
    return __int_as_float(__builtin_amdgcn_update_dpp(
        0, __float_as_int(x), 0x101, 0xF, 0xF, true));
}

// R18 structure (grid 256 x block 1024, 96KB f32 LDS, 1 block/CU, img
// global, K=2 + DPP, 16 waves = 2 pixel-groups x 8 column-splits, all
// constants folded into staging) + 2-COLUMN SOFTWARE ILP:
// R18's post-mortem showed the kernel is latency-bound, not issue-bound
// (-8% VALU ops -> 0% time). Slots 0..5 are valid for EVERY wave
// (s7+40 <= 47 < 49), so the column loop is 3 branchless iterations x 2
// independent inlined column bodies (scheduler interleaves B's ds_reads
// under A's math) + a wave-uniform tail (r=48, s7==0 only). Doubles the
// per-wave independent work that 4 waves/SIMD cannot otherwise provide.
__global__ __launch_bounds__(1024, 4) void statdenoise_kernel(
    const float* __restrict__ img,
    const float* __restrict__ gui,
    const float* __restrict__ est,
    const float* __restrict__ var,
    float* __restrict__ out)
{
    __shared__ float smem[NCH * CH_SZ];   // 96 KB; aliased by reduction later

    // sqrt(0.5*log2(e)*sigma): (a-b)^2 accumulates 0.72135*sig*d2 directly
    const float SQS2[9] = {0.26857913f, 0.26857913f, 0.26857913f,
                           6.00561198f, 6.00561198f, 6.00561198f,
                           2.68579130f, 2.68579130f, 2.68579130f};
    const float G2 = 8.45064899f;   // gamma^2 = 2.907^2

    const int tid  = threadIdx.x;
    const int lane = tid & 63;
    const int sw   = tid >> 6;      // wave 0..15
    const int s7   = sw & 7;        // column-split 0..7
    const int pg   = sw >> 3;       // pixel-group 0..1
    const int tg   = lane & 7;      // t-group 0..7
    const int hwl  = lane >> 3;     // 0..7
    const int t0   = tg * 2;        // owns t0, t0+1
    const int h0   = (blockIdx.x >> 4) << 2;   // tile origin
    const int w0   = (blockIdx.x & 15) << 2;

    // ---- stage 15 channels of the 10x10x16 halo as float4s (edge-clamped;
    //      OOB values masked later by inb, exactly as the clamped loads) ----
    if (tid < 400) {
        const int t   = (tid & 3) << 2;          // t-quad 0,4,8,12
        const int hwq = tid >> 2;                // 0..99
        const int hq  = (hwq * 205) >> 11;       // exact /10 for hwq<1024
        const int wq  = hwq - hq * 10;
        const int hs  = min(max(h0 - 3 + hq, 0), HH - 1);
        const int ws  = min(max(w0 - 3 + wq, 0), WW - 1);
        const int g   = (((hs << 6) + ws) << 4) + t;
        const int p   = hwq * 16 + t;
#pragma unroll
        for (int c = 0; c < 9; ++c) {
            float4 v = *(const float4*)&gui[c * NPIX + g];
            v.x *= SQS2[c]; v.y *= SQS2[c]; v.z *= SQS2[c]; v.w *= SQS2[c];
            *(float4*)&smem[c * CH_SZ + p] = v;
        }
#pragma unroll
        for (int c = 0; c < 3; ++c) {
            *(float4*)&smem[(9 + c) * CH_SZ + p] = *(const float4*)&est[c * NPIX + g];
            float4 v = *(const float4*)&var[c * NPIX + g];
            v.x *= G2; v.y *= G2; v.z *= G2; v.w *= G2;
            *(float4*)&smem[(12 + c) * CH_SZ + p] = v;
        }
    }
    __syncthreads();

    const int pidx = pg * 8 + hwl;        // tile pixel 0..15
    const int th = pidx >> 2, tw = pidx & 3;
    const int hg = h0 + th,  wg = w0 + tw;

    // center values from LDS (center is inside the halo)
    const int lc = (((th + 3) * 10) + (tw + 3)) * 16 + t0;
    float2 gc[9];
#pragma unroll
    for (int c = 0; c < 9; ++c) gc[c] = *(const float2*)&smem[c * CH_SZ + lc];
    float2 ec[3], vc[3];
#pragma unroll
    for (int c = 0; c < 3; ++c) {
        ec[c] = *(const float2*)&smem[(9 + c)  * CH_SZ + lc];
        vc[c] = *(const float2*)&smem[(12 + c) * CH_SZ + lc];   // already x G2
    }
    // column-invariant: center var nonzero (staged value==0 iff var==0)
    bool vcnz[3][2];
#pragma unroll
    for (int c = 0; c < 3; ++c) {
        vcnz[c][0] = (vc[c].x != 0.f);
        vcnz[c][1] = (vc[c].y != 0.f);
    }

    const bool vLo = (t0 != 0);    // dt=-1 valid; also masks DPP boundary garbage
    const bool vHi = (t0 != 14);   // dt=+1 valid; also masks DPP boundary garbage

    float acc[2][4] = {};   // per owned t: {r,g,b,wsum}

    // branchless column body (all LDS addressing in-halo by construction)
    auto doColumn = [&](int dh, int dw) {
        const int lb  = ((th + dh + 3) * 10 + (tw + dw + 3)) * 16 + t0;
        const bool inb = ((unsigned)(hg + dh) < (unsigned)HH) &
                         ((unsigned)(wg + dw) < (unsigned)WW);
        const int hhc = min(max(hg + dh, 0), HH - 1);
        const int wwc = min(max(wg + dw, 0), WW - 1);
        const int gnb = (((hhc << 6) + wwc) << 4) + t0;

        // bilateral over 9 prescaled guidance channels, 6 pairs
        float sb[2][3] = {};
#pragma unroll
        for (int c = 0; c < 9; ++c) {
            float2 m = *(const float2*)&smem[c * CH_SZ + lb];
            float nv[4] = {dpp_up1(m.y), m.x, m.y, dpp_dn1(m.x)};   // t0-1..t0+2
#pragma unroll
            for (int e = 0; e < 2; ++e) {
                float ce = e ? gc[c].y : gc[c].x;
#pragma unroll
                for (int k = 0; k < 3; ++k) {
                    float d = ce - nv[e + k];
                    sb[e][k] = fmaf(d, d, sb[e][k]);
                }
            }
        }

        // membership: mem = (d2==0) | (d2 < vGc+vGn & vc!=0 & vn!=0)
        // (case-verified == reference; OOB neighbors weight-0 -> inb mask)
        bool mem[2][3] = {{true, true, true}, {true, true, true}};
#pragma unroll
        for (int c = 0; c < 3; ++c) {
            float2 em = *(const float2*)&smem[(9 + c)  * CH_SZ + lb];
            float2 vm = *(const float2*)&smem[(12 + c) * CH_SZ + lb];
            float env[4] = {dpp_up1(em.y), em.x, em.y, dpp_dn1(em.x)};
            float vnv[4] = {dpp_up1(vm.y), vm.x, vm.y, dpp_dn1(vm.x)};
#pragma unroll
            for (int e = 0; e < 2; ++e) {
                float ece = e ? ec[c].y : ec[c].x;
                float vce = e ? vc[c].y : vc[c].x;
#pragma unroll
                for (int k = 0; k < 3; ++k) {
                    float d  = ece - env[e + k];
                    float d2 = d * d;
                    float V  = vce + vnv[e + k];           // G2*(vi+vj), pre-folded
                    bool ok = (d2 == 0.f) |
                              ((d2 < V) & vcnz[c][e] & (vnv[e + k] != 0.f));
                    mem[e][k] = mem[e][k] & ok;
                }
            }
        }

        // weights
        float wt[2][3];
#pragma unroll
        for (int e = 0; e < 2; ++e) {
#pragma unroll
            for (int k = 0; k < 3; ++k) {
                bool ok = inb && mem[e][k];
                if (e == 0 && k == 0) ok = ok && vLo;   // tt = t0-1
                if (e == 1 && k == 2) ok = ok && vHi;   // tt = t0+2
                wt[e][k] = ok ? exp2f(-sb[e][k]) : 0.f;
            }
        }

        // accumulate image (global path; consumed last, latency hidden)
#pragma unroll
        for (int c = 0; c < 3; ++c) {
            float2 im = *(const float2*)&img[c * NPIX + gnb];
            float iv[4] = {dpp_up1(im.y), im.x, im.y, dpp_dn1(im.x)};
#pragma unroll
            for (int e = 0; e < 2; ++e) {
                acc[e][c] = fmaf(wt[e][0], iv[e],
                            fmaf(wt[e][1], iv[e + 1],
                            fmaf(wt[e][2], iv[e + 2], acc[e][c])));
            }
        }
#pragma unroll
        for (int e = 0; e < 2; ++e)
            acc[e][3] += wt[e][0] + wt[e][1] + wt[e][2];
    };

    // 3 iterations x 2 independent columns (slots 0..5 valid for ALL waves:
    // s7 + 40 <= 47 < 49); tail slot 6 (r=48) only for s7==0.
    int dhA = s7 / 7 - 3, dwA = s7 % 7 - 3;
#pragma unroll
    for (int i = 0; i < 3; ++i) {
        int dhB = dhA, dwB = dwA + 8;
        while (dwB > 3) { dwB -= 7; ++dhB; }
        doColumn(dhA, dwA);
        doColumn(dhB, dwB);
        dwA += 16;
        while (dwA > 3) { dwA -= 7; ++dhA; }
    }
    if (s7 == 0) doColumn(3, 3);   // r = 48: dh = 48/7-3 = 3, dw = 48%7-3 = 3

    // ---- combine the 8 splits (alias staging LDS after all reads done) ----
    __syncthreads();
    float4* red = (float4*)smem;          // 2048 x float4 = 32 KB < 96 KB
    red[(sw * 64 + lane) * 2 + 0] = make_float4(acc[0][0], acc[0][1], acc[0][2], acc[0][3]);
    red[(sw * 64 + lane) * 2 + 1] = make_float4(acc[1][0], acc[1][1], acc[1][2], acc[1][3]);
    __syncthreads();

    if (tid < 256) {
        const int pg_ = tid >> 7, hwl_ = (tid >> 4) & 7, tg_ = (tid >> 1) & 7, e_ = tid & 1;
        float4 sum = make_float4(0.f, 0.f, 0.f, 0.f);
#pragma unroll
        for (int q = 0; q < 8; ++q) {
            const int swq = pg_ * 8 + q;
            float4 v = red[(swq * 64 + hwl_ * 8 + tg_) * 2 + e_];
            sum.x += v.x; sum.y += v.y; sum.z += v.z; sum.w += v.w;
        }
        const int pidx_ = pg_ * 8 + hwl_;
        const int th_ = pidx_ >> 2, tw_ = pidx_ & 3;
        const int px = ((((h0 + th_) << 6) + (w0 + tw_)) << 4) + tg_ * 2 + e_;
        const float inv = 1.f / sum.w;    // wsum >= 1 (center weight == 1)
        out[0 * NPIX + px] = sum.x * inv;
        out[1 * NPIX + px] = sum.y * inv;
        out[2 * NPIX + px] = sum.z * inv;
    }
}

extern "C" void kernel_launch(void* const* d_in, const int* in_sizes, int n_in,
                              void* d_out, int out_size, void* d_ws, size_t ws_size,
                              hipStream_t stream) {
    const float* img = (const float*)d_in[0];
    const float* gui = (const float*)d_in[1];
    const float* est = (const float*)d_in[2];
    const float* var = (const float*)d_in[3];
    float* out = (float*)d_out;

    dim3 grid(256);     // one 4x4x16 tile per block, 1 block per CU
    dim3 block(1024);   // 16 waves: 2 pixel-groups x 8 column-splits
    statdenoise_kernel<<<grid, block, 0, stream>>>(img, gui, est, var, out);
}

// Round 20
// 31.588 us; speedup vs baseline: 4.8722x; 4.8722x over previous
//
#include <hip/hip_runtime.h>
#include <math.h>

#define HH 64
#define WW 64
#define TT 16
#define NPIX (HH * WW * TT)   // 65536
#define HALO 10               // 4 + 2*3
#define HWH  (HALO * HALO)    // 100 halo (h,w) positions
#define CH_SZ (HWH * TT)      // 1600 floats per channel
#define NCH 15                // gui(9, prescaled) + est(3) + var(3, G2-folded/NaN)

// lane i <- lane i-1 within 16-lane DPP rows (row_shr:1), 0-fill at row start.
__device__ __forceinline__ float dpp_up1(float x) {
    return __int_as_float(__builtin_amdgcn_update_dpp(
        0, __float_as_int(x), 0x111, 0xF, 0xF, true));
}
// lane i <- lane i+1 within 16-lane DPP rows (row_shl:1), 0-fill at row end.
__device__ __forceinline__ float dpp_dn1(float x) {
    return __int_as_float(__builtin_amdgcn_update_dpp(
        0, __float_as_int(x), 0x101, 0xF, 0xF, true));
}

// R18 champion (grid 256 x block 1024, 96KB f32 LDS, 1 blk/CU, K=2 + DPP,
// 16 waves = 2 pixel-groups x 8 column-splits, constants folded at staging;
// 25.3us replay-stable) + two minimal changes:
//  (1) img loads SOFTWARE-PIPELINED one column ahead (6 VGPR state only --
//      R19 proved whole-body ILP spills at the 1024-thread VGPR cap). The
//      ~200cy L2 latency now hides under the next column's ~350cy compute.
//  (2) var staged as (var==0 ? NaN : G2*var): membership = (d2==0)|(d2<V).
//      NaN kills d2<V exactly where reference kills (v==0 & d!=0); d2==0
//      rescue preserved (both-zero -> w=0.5 -> member). Drops all vnz ops.
__global__ __launch_bounds__(1024, 4) void statdenoise_kernel(
    const float* __restrict__ img,
    const float* __restrict__ gui,
    const float* __restrict__ est,
    const float* __restrict__ var,
    float* __restrict__ out)
{
    __shared__ float smem[NCH * CH_SZ];   // 96 KB; aliased by reduction later

    // sqrt(0.5*log2(e)*sigma): (a-b)^2 accumulates 0.72135*sig*d2 directly
    const float SQS2[9] = {0.26857913f, 0.26857913f, 0.26857913f,
                           6.00561198f, 6.00561198f, 6.00561198f,
                           2.68579130f, 2.68579130f, 2.68579130f};
    const float G2 = 8.45064899f;   // gamma^2 = 2.907^2

    const int tid  = threadIdx.x;
    const int lane = tid & 63;
    const int sw   = tid >> 6;      // wave 0..15
    const int s7   = sw & 7;        // column-split 0..7
    const int pg   = sw >> 3;       // pixel-group 0..1
    const int tg   = lane & 7;      // t-group 0..7
    const int hwl  = lane >> 3;     // 0..7
    const int t0   = tg * 2;        // owns t0, t0+1
    const int h0   = (blockIdx.x >> 4) << 2;   // tile origin
    const int w0   = (blockIdx.x & 15) << 2;

    // ---- stage 15 channels of the 10x10x16 halo as float4s (edge-clamped;
    //      OOB values masked later by inb, exactly as the clamped loads) ----
    if (tid < 400) {
        const int t   = (tid & 3) << 2;          // t-quad 0,4,8,12
        const int hwq = tid >> 2;                // 0..99
        const int hq  = (hwq * 205) >> 11;       // exact /10 for hwq<1024
        const int wq  = hwq - hq * 10;
        const int hs  = min(max(h0 - 3 + hq, 0), HH - 1);
        const int ws  = min(max(w0 - 3 + wq, 0), WW - 1);
        const int g   = (((hs << 6) + ws) << 4) + t;
        const int p   = hwq * 16 + t;
#pragma unroll
        for (int c = 0; c < 9; ++c) {
            float4 v = *(const float4*)&gui[c * NPIX + g];
            v.x *= SQS2[c]; v.y *= SQS2[c]; v.z *= SQS2[c]; v.w *= SQS2[c];
            *(float4*)&smem[c * CH_SZ + p] = v;
        }
#pragma unroll
        for (int c = 0; c < 3; ++c) {
            *(float4*)&smem[(9 + c) * CH_SZ + p] = *(const float4*)&est[c * NPIX + g];
            float4 v = *(const float4*)&var[c * NPIX + g];
            v.x = (v.x == 0.f) ? NAN : v.x * G2;
            v.y = (v.y == 0.f) ? NAN : v.y * G2;
            v.z = (v.z == 0.f) ? NAN : v.z * G2;
            v.w = (v.w == 0.f) ? NAN : v.w * G2;
            *(float4*)&smem[(12 + c) * CH_SZ + p] = v;
        }
    }
    __syncthreads();

    const int pidx = pg * 8 + hwl;        // tile pixel 0..15
    const int th = pidx >> 2, tw = pidx & 3;
    const int hg = h0 + th,  wg = w0 + tw;

    // center values from LDS (center is inside the halo)
    const int lc = (((th + 3) * 10) + (tw + 3)) * 16 + t0;
    float2 gc[9];
#pragma unroll
    for (int c = 0; c < 9; ++c) gc[c] = *(const float2*)&smem[c * CH_SZ + lc];
    float2 ec[3], vc[3];
#pragma unroll
    for (int c = 0; c < 3; ++c) {
        ec[c] = *(const float2*)&smem[(9 + c)  * CH_SZ + lc];
        vc[c] = *(const float2*)&smem[(12 + c) * CH_SZ + lc];   // G2-folded / NaN
    }

    const bool vLo = (t0 != 0);    // dt=-1 valid; also masks DPP boundary garbage
    const bool vHi = (t0 != 14);   // dt=+1 valid; also masks DPP boundary garbage

    float acc[2][4] = {};   // per owned t: {r,g,b,wsum}

    // ---- img pipeline prologue: load column 0's img (clamped addr) ----
    int dh = s7 / 7 - 3, dw = s7 % 7 - 3;   // column r = s7, then += 8
    int hhc = min(max(hg + dh, 0), HH - 1);
    int wwc = min(max(wg + dw, 0), WW - 1);
    int gnb = (((hhc << 6) + wwc) << 4) + t0;
    float2 imA0 = *(const float2*)&img[0 * NPIX + gnb];
    float2 imA1 = *(const float2*)&img[1 * NPIX + gnb];
    float2 imA2 = *(const float2*)&img[2 * NPIX + gnb];

    for (int r = s7; r < 49; r += 8) {
        // halo coords are ALWAYS in range: th+dh+3 in [0,9], tw+dw+3 in [0,9]
        const int lb  = ((th + dh + 3) * 10 + (tw + dw + 3)) * 16 + t0;
        const bool inb = ((unsigned)(hg + dh) < (unsigned)HH) &
                         ((unsigned)(wg + dw) < (unsigned)WW);

        // next column's coords + img prefetch (clamped addr: safe past end)
        int dhn = dh, dwn = dw + 8;
        while (dwn > 3) { dwn -= 7; ++dhn; }
        const int hhn = min(max(hg + dhn, 0), HH - 1);
        const int wwn = min(max(wg + dwn, 0), WW - 1);
        const int gnbn = (((hhn << 6) + wwn) << 4) + t0;
        float2 imB0 = *(const float2*)&img[0 * NPIX + gnbn];
        float2 imB1 = *(const float2*)&img[1 * NPIX + gnbn];
        float2 imB2 = *(const float2*)&img[2 * NPIX + gnbn];

        // ---- bilateral over 9 prescaled guidance channels, 6 pairs ----
        float sb[2][3] = {};
#pragma unroll
        for (int c = 0; c < 9; ++c) {
            float2 m = *(const float2*)&smem[c * CH_SZ + lb];
            float nv[4] = {dpp_up1(m.y), m.x, m.y, dpp_dn1(m.x)};   // t0-1..t0+2
#pragma unroll
            for (int e = 0; e < 2; ++e) {
                float ce = e ? gc[c].y : gc[c].x;
#pragma unroll
                for (int k = 0; k < 3; ++k) {
                    float d = ce - nv[e + k];
                    sb[e][k] = fmaf(d, d, sb[e][k]);
                }
            }
        }

        // ---- membership: (d2==0) | (d2 < V), V NaN-poisoned where var==0 ----
        bool mem[2][3] = {{true, true, true}, {true, true, true}};
#pragma unroll
        for (int c = 0; c < 3; ++c) {
            float2 em = *(const float2*)&smem[(9 + c)  * CH_SZ + lb];
            float2 vm = *(const float2*)&smem[(12 + c) * CH_SZ + lb];
            float env[4] = {dpp_up1(em.y), em.x, em.y, dpp_dn1(em.x)};
            float vnv[4] = {dpp_up1(vm.y), vm.x, vm.y, dpp_dn1(vm.x)};
#pragma unroll
            for (int e = 0; e < 2; ++e) {
                float ece = e ? ec[c].y : ec[c].x;
                float vce = e ? vc[c].y : vc[c].x;
#pragma unroll
                for (int k = 0; k < 3; ++k) {
                    float d  = ece - env[e + k];
                    float d2 = d * d;
                    float V  = vce + vnv[e + k];   // NaN if either var was 0
                    bool ok = (d2 == 0.f) | (d2 < V);
                    mem[e][k] = mem[e][k] & ok;
                }
            }
        }

        // ---- weights ----
        float wt[2][3];
#pragma unroll
        for (int e = 0; e < 2; ++e) {
#pragma unroll
            for (int k = 0; k < 3; ++k) {
                bool ok = inb && mem[e][k];
                if (e == 0 && k == 0) ok = ok && vLo;   // tt = t0-1
                if (e == 1 && k == 2) ok = ok && vHi;   // tt = t0+2
                wt[e][k] = ok ? exp2f(-sb[e][k]) : 0.f;
            }
        }

        // ---- accumulate image (pipelined: loaded one column ago) ----
        {
            float iv0[4] = {dpp_up1(imA0.y), imA0.x, imA0.y, dpp_dn1(imA0.x)};
            float iv1[4] = {dpp_up1(imA1.y), imA1.x, imA1.y, dpp_dn1(imA1.x)};
            float iv2[4] = {dpp_up1(imA2.y), imA2.x, imA2.y, dpp_dn1(imA2.x)};
#pragma unroll
            for (int e = 0; e < 2; ++e) {
                acc[e][0] = fmaf(wt[e][0], iv0[e],
                            fmaf(wt[e][1], iv0[e + 1],
                            fmaf(wt[e][2], iv0[e + 2], acc[e][0])));
                acc[e][1] = fmaf(wt[e][0], iv1[e],
                            fmaf(wt[e][1], iv1[e + 1],
                            fmaf(wt[e][2], iv1[e + 2], acc[e][1])));
                acc[e][2] = fmaf(wt[e][0], iv2[e],
                            fmaf(wt[e][1], iv2[e + 1],
                            fmaf(wt[e][2], iv2[e + 2], acc[e][2])));
                acc[e][3] += wt[e][0] + wt[e][1] + wt[e][2];
            }
        }

        // rotate pipeline state
        imA0 = imB0; imA1 = imB1; imA2 = imB2;
        dh = dhn; dw = dwn;
    }

    // ---- combine the 8 splits (alias staging LDS after all reads done) ----
    __syncthreads();
    float4* red = (float4*)smem;          // 2048 x float4 = 32 KB < 96 KB
    red[(sw * 64 + lane) * 2 + 0] = make_float4(acc[0][0], acc[0][1], acc[0][2], acc[0][3]);
    red[(sw * 64 + lane) * 2 + 1] = make_float4(acc[1][0], acc[1][1], acc[1][2], acc[1][3]);
    __syncthreads();

    if (tid < 256) {
        const int pg_ = tid >> 7, hwl_ = (tid >> 4) & 7, tg_ = (tid >> 1) & 7, e_ = tid & 1;
        float4 sum = make_float4(0.f, 0.f, 0.f, 0.f);
#pragma unroll
        for (int q = 0; q < 8; ++q) {
            const int swq = pg_ * 8 + q;
            float4 v = red[(swq * 64 + hwl_ * 8 + tg_) * 2 + e_];
            sum.x += v.x; sum.y += v.y; sum.z += v.z; sum.w += v.w;
        }
        const int pidx_ = pg_ * 8 + hwl_;
        const int th_ = pidx_ >> 2, tw_ = pidx_ & 3;
        const int px = ((((h0 + th_) << 6) + (w0 + tw_)) << 4) + tg_ * 2 + e_;
        const float inv = 1.f / sum.w;    // wsum >= 1 (center weight == 1)
        out[0 * NPIX + px] = sum.x * inv;
        out[1 * NPIX + px] = sum.y * inv;
        out[2 * NPIX + px] = sum.z * inv;
    }
}

extern "C" void kernel_launch(void* const* d_in, const int* in_sizes, int n_in,
                              void* d_out, int out_size, void* d_ws, size_t ws_size,
                              hipStream_t stream) {
    const float* img = (const float*)d_in[0];
    const float* gui = (const float*)d_in[1];
    const float* est = (const float*)d_in[2];
    const float* var = (const float*)d_in[3];
    float* out = (float*)d_out;

    dim3 grid(256);     // one 4x4x16 tile per block, 1 block per CU
    dim3 block(1024);   // 16 waves: 2 pixel-groups x 8 column-splits
    statdenoise_kernel<<<grid, block, 0, stream>>>(img, gui, est, var, out);
}

// Round 21
// 25.328 us; speedup vs baseline: 6.0763x; 1.2471x over previous
//
#include <hip/hip_runtime.h>

#define HH 64
#define WW 64
#define TT 16
#define NPIX (HH * WW * TT)   // 65536
#define HALO 10               // 4 + 2*3
#define HWH  (HALO * HALO)    // 100 halo (h,w) positions
#define CH_SZ (HWH * TT)      // 1600 floats per channel
#define NCH 15                // gui(9, sqrt-sigma-prescaled) + est(3) + var(3)

// lane i <- lane i-1 within 16-lane DPP rows (row_shr:1), 0-fill at row start.
__device__ __forceinline__ float dpp_up1(float x) {
    return __int_as_float(__builtin_amdgcn_update_dpp(
        0, __float_as_int(x), 0x111, 0xF, 0xF, true));
}
// lane i <- lane i+1 within 16-lane DPP rows (row_shl:1), 0-fill at row end.
__device__ __forceinline__ float dpp_dn1(float x) {
    return __int_as_float(__builtin_amdgcn_update_dpp(
        0, __float_as_int(x), 0x101, 0xF, 0xF, true));
}

// CHAMPION (R17, 25.29us, replay-stable): grid 256 x block 1024, 96KB f32
// LDS, 1 block/CU, img global, K=2 + DPP, 16 waves = 2 pixel-groups x 8
// column-splits; gui prescaled by sqrt(SIG) at staging; membership
// simplified (case-verified == reference). Rounds 18-20 proved this body
// is at a latency-structural floor: op-trims neutral (R18), manual ILP
// spills (R19) or regresses (R20), occupancy routes all closed
// (spill at >64 VGPR/1024thr; L2-thrash or replay-race at >=2 blk/CU).
__global__ __launch_bounds__(1024, 4) void statdenoise_kernel(
    const float* __restrict__ img,
    const float* __restrict__ gui,
    const float* __restrict__ est,
    const float* __restrict__ var,
    float* __restrict__ out)
{
    __shared__ float smem[NCH * CH_SZ];   // 96 KB; aliased by reduction later

    const float SQS[9] = {0.31622776601683794f, 0.31622776601683794f, 0.31622776601683794f,
                          7.0710678118654755f,  7.0710678118654755f,  7.0710678118654755f,
                          3.1622776601683795f,  3.1622776601683795f,  3.1622776601683795f};
    const float G2 = 2.907f * 2.907f;   // gamma^2

    const int tid  = threadIdx.x;
    const int lane = tid & 63;
    const int sw   = tid >> 6;      // wave 0..15
    const int s7   = sw & 7;        // column-split 0..7
    const int pg   = sw >> 3;       // pixel-group 0..1
    const int tg   = lane & 7;      // t-group 0..7
    const int hwl  = lane >> 3;     // 0..7
    const int t0   = tg * 2;        // owns t0, t0+1
    const int h0   = (blockIdx.x >> 4) << 2;   // tile origin
    const int w0   = (blockIdx.x & 15) << 2;

    // ---- stage 15 channels of the 10x10x16 halo (edge-clamped; OOB
    //      values masked later by inb, exactly as the clamped loads) ----
#pragma unroll
    for (int rep = 0; rep < 2; ++rep) {
        const int q = tid + rep * 1024;
        if (q < CH_SZ) {
            const int t   = q & 15;
            const int hwq = q >> 4;                  // 0..99
            const int hq  = (hwq * 205) >> 11;       // exact /10 for hwq<1024
            const int wq  = hwq - hq * 10;
            const int hs  = min(max(h0 - 3 + hq, 0), HH - 1);
            const int ws  = min(max(w0 - 3 + wq, 0), WW - 1);
            const int g   = (((hs << 6) + ws) << 4) + t;
#pragma unroll
            for (int c = 0; c < 9; ++c)
                smem[c * CH_SZ + q] = gui[c * NPIX + g] * SQS[c];   // prescaled
#pragma unroll
            for (int c = 0; c < 3; ++c) {
                smem[(9 + c)  * CH_SZ + q] = est[c * NPIX + g];
                smem[(12 + c) * CH_SZ + q] = var[c * NPIX + g];
            }
        }
    }
    __syncthreads();

    const int pidx = pg * 8 + hwl;        // tile pixel 0..15
    const int th = pidx >> 2, tw = pidx & 3;
    const int hg = h0 + th,  wg = w0 + tw;

    // center values from LDS (center is inside the halo)
    const int lc = (((th + 3) * 10) + (tw + 3)) * 16 + t0;
    float2 gc[9];
#pragma unroll
    for (int c = 0; c < 9; ++c) gc[c] = *(const float2*)&smem[c * CH_SZ + lc];
    float2 ec[3], vc[3];
#pragma unroll
    for (int c = 0; c < 3; ++c) {
        ec[c] = *(const float2*)&smem[(9 + c)  * CH_SZ + lc];
        vc[c] = *(const float2*)&smem[(12 + c) * CH_SZ + lc];
    }

    const bool vLo = (t0 != 0);    // dt=-1 valid; also masks DPP boundary garbage
    const bool vHi = (t0 != 14);   // dt=+1 valid; also masks DPP boundary garbage

    float acc[2][4] = {};   // per owned t: {r,g,b,wsum}

    int dh = s7 / 7 - 3, dw = s7 % 7 - 3;   // column r = s7, then += 8
    for (int r = s7; r < 49; r += 8) {
        // halo coords are ALWAYS in range: th+dh+3 in [0,9], tw+dw+3 in [0,9]
        const int lb  = ((th + dh + 3) * 10 + (tw + dw + 3)) * 16 + t0;
        const bool inb = ((unsigned)(hg + dh) < (unsigned)HH) &
                         ((unsigned)(wg + dw) < (unsigned)WW);
        // clamped global offset for img
        const int hhc = min(max(hg + dh, 0), HH - 1);
        const int wwc = min(max(wg + dw, 0), WW - 1);
        const int gnb = (((hhc << 6) + wwc) << 4) + t0;

        // ---- bilateral over 9 prescaled guidance channels, 6 pairs ----
        float sb[2][3] = {};
#pragma unroll
        for (int c = 0; c < 9; ++c) {
            float2 m = *(const float2*)&smem[c * CH_SZ + lb];
            float nv[4] = {dpp_up1(m.y), m.x, m.y, dpp_dn1(m.x)};   // t0-1..t0+2
#pragma unroll
            for (int e = 0; e < 2; ++e) {
                float ce = e ? gc[c].y : gc[c].x;
#pragma unroll
                for (int k = 0; k < 3; ++k) {
                    float d = ce - nv[e + k];
                    sb[e][k] = fmaf(d, d, sb[e][k]);   // sig folded into inputs
                }
            }
        }

        // ---- membership (division-free Welch t-test, simplified) ----
        // mem = (d2==0) | (d2 < G2*V & vce!=0 & vnv!=0). Case-verified vs
        // reference (incl. v==0 kills and num==den==0 -> 0.5 -> member).
        // OOB h/w neighbors provably get weight 0 -> masked by inb.
        bool mem[2][3] = {{true, true, true}, {true, true, true}};
#pragma unroll
        for (int c = 0; c < 3; ++c) {
            float2 em = *(const float2*)&smem[(9 + c)  * CH_SZ + lb];
            float2 vm = *(const float2*)&smem[(12 + c) * CH_SZ + lb];
            float env[4] = {dpp_up1(em.y), em.x, em.y, dpp_dn1(em.x)};
            float vnv[4] = {dpp_up1(vm.y), vm.x, vm.y, dpp_dn1(vm.x)};
#pragma unroll
            for (int e = 0; e < 2; ++e) {
                float ece = e ? ec[c].y : ec[c].x;
                float vce = e ? vc[c].y : vc[c].x;
#pragma unroll
                for (int k = 0; k < 3; ++k) {
                    float d  = ece - env[e + k];
                    float d2 = d * d;
                    float V  = vce + vnv[e + k];
                    bool ok = (d2 == 0.f) |
                              ((d2 < G2 * V) & !((vce == 0.f) | (vnv[e + k] == 0.f)));
                    mem[e][k] = mem[e][k] & ok;
                }
            }
        }

        // ---- weights ----
        float wt[2][3];
#pragma unroll
        for (int e = 0; e < 2; ++e) {
#pragma unroll
            for (int k = 0; k < 3; ++k) {
                bool ok = inb && mem[e][k];
                if (e == 0 && k == 0) ok = ok && vLo;   // tt = t0-1
                if (e == 1 && k == 2) ok = ok && vHi;   // tt = t0+2
                wt[e][k] = ok ? __expf(-0.5f * sb[e][k]) : 0.f;
            }
        }

        // ---- accumulate image (global path; consumed last, latency hidden) ----
#pragma unroll
        for (int c = 0; c < 3; ++c) {
            float2 im = *(const float2*)&img[c * NPIX + gnb];
            float iv[4] = {dpp_up1(im.y), im.x, im.y, dpp_dn1(im.x)};
#pragma unroll
            for (int e = 0; e < 2; ++e) {
                acc[e][c] = fmaf(wt[e][0], iv[e],
                            fmaf(wt[e][1], iv[e + 1],
                            fmaf(wt[e][2], iv[e + 2], acc[e][c])));
            }
        }
#pragma unroll
        for (int e = 0; e < 2; ++e)
            acc[e][3] += wt[e][0] + wt[e][1] + wt[e][2];

        dw += 8;
        while (dw > 3) { dw -= 7; ++dh; }
    }

    // ---- combine the 8 splits (alias staging LDS after all reads done) ----
    __syncthreads();
    float4* red = (float4*)smem;          // 2048 x float4 = 32 KB < 96 KB
    red[(sw * 64 + lane) * 2 + 0] = make_float4(acc[0][0], acc[0][1], acc[0][2], acc[0][3]);
    red[(sw * 64 + lane) * 2 + 1] = make_float4(acc[1][0], acc[1][1], acc[1][2], acc[1][3]);
    __syncthreads();

    if (tid < 256) {
        const int pg_ = tid >> 7, hwl_ = (tid >> 4) & 7, tg_ = (tid >> 1) & 7, e_ = tid & 1;
        float4 sum = make_float4(0.f, 0.f, 0.f, 0.f);
#pragma unroll
        for (int q = 0; q < 8; ++q) {
            const int swq = pg_ * 8 + q;
            float4 v = red[(swq * 64 + hwl_ * 8 + tg_) * 2 + e_];
            sum.x += v.x; sum.y += v.y; sum.z += v.z; sum.w += v.w;
        }
        const int pidx_ = pg_ * 8 + hwl_;
        const int th_ = pidx_ >> 2, tw_ = pidx_ & 3;
        const int px = ((((h0 + th_) << 6) + (w0 + tw_)) << 4) + tg_ * 2 + e_;
        const float inv = 1.f / sum.w;    // wsum >= 1 (center weight == 1)
        out[0 * NPIX + px] = sum.x * inv;
        out[1 * NPIX + px] = sum.y * inv;
        out[2 * NPIX + px] = sum.z * inv;
    }
}

extern "C" void kernel_launch(void* const* d_in, const int* in_sizes, int n_in,
                              void* d_out, int out_size, void* d_ws, size_t ws_size,
                              hipStream_t stream) {
    const float* img = (const float*)d_in[0];
    const float* gui = (const float*)d_in[1];
    const float* est = (const float*)d_in[2];
    const float* var = (const float*)d_in[3];
    float* out = (float*)d_out;

    dim3 grid(256);     // one 4x4x16 tile per block, 1 block per CU
    dim3 block(1024);   // 16 waves: 2 pixel-groups x 8 column-splits
    statdenoise_kernel<<<grid, block, 0, stream>>>(img, gui, est, var, out);
}